// Round 17
// baseline (259.005 us; speedup 1.0000x reference)
//
#include <hip/hip_runtime.h>
#include <hip/hip_bf16.h>

#define S_LEN 4096
#define DMODEL 1024
#define NHEAD 16
#define DK 64

typedef __hip_bfloat16 bf16;
typedef __attribute__((ext_vector_type(8))) __bf16 bf16x8;
typedef __attribute__((ext_vector_type(4))) float f32x4;

__device__ __forceinline__ f32x4 mfma16(bf16x8 a, bf16x8 b, f32x4 c) {
    return __builtin_amdgcn_mfma_f32_16x16x32_bf16(a, b, c, 0, 0, 0);
}

// async global->LDS, 16B per lane. LDS dest is wave-uniform base + lane*16.
__device__ __forceinline__ void async16(const bf16* g, bf16* l) {
    __builtin_amdgcn_global_load_lds(
        (const __attribute__((address_space(1))) unsigned int*)g,
        (__attribute__((address_space(3))) unsigned int*)l, 16, 0, 0);
}

__device__ __forceinline__ bf16x8 cvt8(float4 a, float4 b) {
    bf16x8 r;
    r[0] = (__bf16)a.x; r[1] = (__bf16)a.y; r[2] = (__bf16)a.z; r[3] = (__bf16)a.w;
    r[4] = (__bf16)b.x; r[5] = (__bf16)b.y; r[6] = (__bf16)b.z; r[7] = (__bf16)b.w;
    return r;
}

// pack two f32 -> u32 of 2 bf16 (RNE)
__device__ __forceinline__ unsigned int pkbf(float lo, float hi) {
    unsigned short a = __bfloat16_as_ushort(__float2bfloat16(lo));
    unsigned short b = __bfloat16_as_ushort(__float2bfloat16(hi));
    return (unsigned int)a | ((unsigned int)b << 16);
}

// XOR-swizzled index into a [rows][64] bf16 tile (128B rows): 16B slot ^ (row&7).
__device__ __forceinline__ int swz8(int row, int col8) {  // col8 = col>>3
    return row * 64 + ((col8 ^ (row & 7)) << 3);
}
// Same for [rows][128] bf16 tiles (256B rows, 16 slots; XOR spreads 8 rows).
__device__ __forceinline__ int vswz(int row, int col8) {
    return row * 128 + ((col8 ^ (row & 7)) << 3);
}

// K-row placement permutation (R10-verified): position p holds original kv
// with p = [b5 b2 b4 b3 b1 b0]. Makes swapped-QK^T leave each q-row's P
// values lane-local in PV A-frag order -> zero-shuffle PV.
__device__ __forceinline__ int kperm(int kv) {
    return (kv & 0x23) | ((kv & 0x04) << 2) | ((kv & 0x18) >> 1);
}

// C[M][N] = A[M][K=1024] * B[N][K]^T, 128x128 tile, bf16 MFMA compute.
// MODE 0 (Q/K proj): A = f32 x, out = bf16 head-major [h][s][dk], scale folded
// MODE 1 (OUT proj): A = bf16 ws (global_load_lds), out = f32 row-major C[m][n]
// MODE 2 (V^T proj): A = f32 Wv, B = f32 x, out = bf16 [h=m>>6][d=m&63][s=n];
//                    block indices swapped (gridDim = (M-tiles, N-tiles) there)
template <int MODE>
__device__ __forceinline__ void gemm_body(const void* Ap, const float* B,
                                          void* Cp, float scale) {
    constexpr int K = DMODEL;
    __shared__ bf16 As[128 * 32];
    __shared__ bf16 Bs[128 * 32];

    const int t = threadIdx.x;
    const int lane = t & 63;
    const int l15 = lane & 15, lhi = lane >> 4;
    const int wave = t >> 6;
    const int wm = wave >> 1, wn = wave & 1;
    const int bm = (MODE == 2) ? blockIdx.x : blockIdx.y;
    const int bn = (MODE == 2) ? blockIdx.y : blockIdx.x;

    const int srow = t >> 2, scol = (t & 3) * 8;

    const float* gB = B + (size_t)(bn * 128 + srow) * K + scol;
    const float* gAf = (const float*)Ap + (size_t)(bm * 128 + srow) * K + scol;
    const bf16* gAb = (const bf16*)Ap + (size_t)(bm * 128 + srow) * K + scol;

    f32x4 acc[4][4];
#pragma unroll
    for (int i = 0; i < 4; ++i)
#pragma unroll
        for (int j = 0; j < 4; ++j) acc[i][j] = (f32x4){0.f, 0.f, 0.f, 0.f};

    for (int kt = 0; kt < K / 32; ++kt) {
        if (MODE != 1) {
            float4 a0 = *(const float4*)(gAf + kt * 32);
            float4 a1 = *(const float4*)(gAf + kt * 32 + 4);
            *(bf16x8*)&As[srow * 32 + scol] = cvt8(a0, a1);
            float4 a2 = *(const float4*)(gAf + kt * 32 + 64 * K);
            float4 a3 = *(const float4*)(gAf + kt * 32 + 64 * K + 4);
            *(bf16x8*)&As[2048 + srow * 32 + scol] = cvt8(a2, a3);
        } else {
            async16(gAb + kt * 32,          (bf16*)As + t * 8);
            async16(gAb + kt * 32 + 64 * K, (bf16*)As + 2048 + t * 8);
        }
        {
            float4 b0 = *(const float4*)(gB + kt * 32);
            float4 b1 = *(const float4*)(gB + kt * 32 + 4);
            *(bf16x8*)&Bs[srow * 32 + scol] = cvt8(b0, b1);
            float4 b2 = *(const float4*)(gB + kt * 32 + 64 * K);
            float4 b3 = *(const float4*)(gB + kt * 32 + 64 * K + 4);
            *(bf16x8*)&Bs[2048 + srow * 32 + scol] = cvt8(b2, b3);
        }
        __syncthreads();

        bf16x8 af[4], bv[4];
#pragma unroll
        for (int mt = 0; mt < 4; ++mt)
            af[mt] = *(const bf16x8*)&As[(wm * 64 + mt * 16 + l15) * 32 + lhi * 8];
#pragma unroll
        for (int nt = 0; nt < 4; ++nt)
            bv[nt] = *(const bf16x8*)&Bs[(wn * 64 + nt * 16 + l15) * 32 + lhi * 8];
#pragma unroll
        for (int mt = 0; mt < 4; ++mt)
#pragma unroll
            for (int nt = 0; nt < 4; ++nt)
                acc[mt][nt] = mfma16(af[mt], bv[nt], acc[mt][nt]);
        __syncthreads();
    }

#pragma unroll
    for (int mt = 0; mt < 4; ++mt)
#pragma unroll
        for (int nt = 0; nt < 4; ++nt)
#pragma unroll
            for (int r = 0; r < 4; ++r) {
                int m = bm * 128 + wm * 64 + mt * 16 + lhi * 4 + r;
                int n = bn * 128 + wn * 64 + nt * 16 + l15;
                float v = acc[mt][nt][r] * scale;
                if (MODE == 0)
                    ((bf16*)Cp)[((size_t)(n >> 6) * S_LEN + m) * DK + (n & 63)] =
                        __float2bfloat16(v);
                else if (MODE == 1)
                    ((float*)Cp)[(size_t)m * DMODEL + n] = v;
                else  // MODE 2: [h][d][s]
                    ((bf16*)Cp)[((size_t)(m >> 6) * DK + (m & 63)) * S_LEN + n] =
                        __float2bfloat16(v);
            }
}

// One launch, grid (8, 32, 3): z=0 Q, z=1 K (MODE 0), z=2 V^T (MODE 2,
// block indices swapped inside: x = M-tiles of DMODEL, y = N-tiles of S).
__global__ __launch_bounds__(256) void qkv_proj(const float* __restrict__ x,
                                                const float* __restrict__ Wq,
                                                const float* __restrict__ Wk,
                                                const float* __restrict__ Wv,
                                                bf16* __restrict__ q,
                                                bf16* __restrict__ k,
                                                bf16* __restrict__ vT) {
    const int z = blockIdx.z;
    if (z == 2) {
        gemm_body<2>(Wv, x, vT, 1.0f);
    } else {
        const float* B = (z == 0) ? Wq : Wk;
        bf16* out = (z == 0) ? q : k;
        float scale = (z == 0) ? 0.18033688011112042f : 1.0f;  // (1/sqrt64)*log2e
        gemm_body<0>(x, B, out, scale);
    }
}

__global__ __launch_bounds__(256) void out_proj(const bf16* __restrict__ A,
                                                const float* __restrict__ Wo,
                                                float* __restrict__ C) {
    gemm_body<1>(A, Wo, C, 1.0f);
}

// Flash attention, causal, KVBLK=128 (two 64-kv subtiles per step: halves the
// serial-chain iterations and barrier pairs vs the KVBLK=64 structure; one
// reduce/pack sequence covers 128 kv). 256 threads = 4 waves x 16 q-rows.
// Grid 1024, balanced mapping (stride-256 classes sum to 66 steps).
// Single-buffer LDS 32KB. V PRE-TRANSPOSED [h][d][s]. K rows at kperm'd
// positions per 64-subtile -> zero-shuffle PV. Scalar m/l, 2-shfl reductions,
// T13 defer-max, T5 setprio, T14 register prefetch (8x uint4).
// NOTE: plain launch_bounds(256) — the earlier (256,4) min-waves clamp forced
// a 64-VGPR allocation and spilled ~110 live regs to scratch (WRITE_SIZE
// 484MB, MfmaUtil 0.6%). Compiler must be free to take ~128 VGPRs here.
__global__ __launch_bounds__(256) void attn_kernel(const bf16* __restrict__ Q,
                                                   const bf16* __restrict__ Kg,
                                                   const bf16* __restrict__ Vtg,
                                                   bf16* __restrict__ O) {
    __shared__ bf16 Ks[2][64 * 64];   // [kv-subtile][swizzled kperm'd rows]
    __shared__ bf16 Vt[64 * 128];     // [d][kv 0..127], vswz

    const int b = blockIdx.x;
    const int t = threadIdx.x;
    const int lane = t & 63;
    const int l15 = lane & 15, lhi = lane >> 4;
    const int wave = t >> 6;

    // K staging: 128 rows x 2 threads/row, 4 x 16B slots each
    const int srowK = t >> 1, halfK = t & 1;
    const int subK = srowK >> 6;
    const int kposK = kperm(srowK & 63);
    // V staging: 64 d-rows x 4 threads/row, 4 x 16B slots each (256B rows)
    const int srowV = t >> 2, qv = t & 3;

    // balanced unit mapping: stride-256 classes sum to 66 128-steps
    const int g = b >> 8, idx = b & 255;
    const int j = idx >> 4, h = idx & 15;
    const int qt = (g == 0) ? (63 - j) : (g == 1) ? (32 + j)
                 : (g == 2) ? (31 - j) : j;

    const bf16* qh = Q + (size_t)h * S_LEN * DK;
    const bf16* kh = Kg + (size_t)h * S_LEN * DK;
    const bf16* vh = Vtg + (size_t)h * DK * S_LEN;  // [d][s]

    const int q0w = qt * 64 + wave * 16;

    // Q B-fragments: row=q0w+l15, k chunks (scale+log2e folded in Q)
    bf16x8 qf0 = *(const bf16x8*)&qh[(size_t)(q0w + l15) * DK + lhi * 8];
    bf16x8 qf1 = *(const bf16x8*)&qh[(size_t)(q0w + l15) * DK + 32 + lhi * 8];

    float m_s = -3.0e38f, l_s = 0.f;  // scalar state for q = q0w + l15
    f32x4 oacc[4];
#pragma unroll
    for (int d = 0; d < 4; ++d) oacc[d] = (f32x4){0.f, 0.f, 0.f, 0.f};

    const int NT2 = (qt + 2) >> 1;  // ceil((qt+1)/2) 128-wide steps
    uint4 kr[4], vr[4];

    auto load_regs = [&](int kt) {
        const int k0 = kt * 128;
#pragma unroll
        for (int c = 0; c < 4; ++c)
            kr[c] = *(const uint4*)&kh[(size_t)(k0 + srowK) * DK +
                                       (halfK * 4 + c) * 8];
#pragma unroll
        for (int c = 0; c < 4; ++c)
            vr[c] = *(const uint4*)&vh[(size_t)srowV * S_LEN + k0 +
                                       (qv * 4 + c) * 8];
    };
    auto write_lds = [&]() {
#pragma unroll
        for (int c = 0; c < 4; ++c)
            *(uint4*)&Ks[subK][swz8(kposK, halfK * 4 + c)] = kr[c];
#pragma unroll
        for (int c = 0; c < 4; ++c)
            *(uint4*)&Vt[vswz(srowV, qv * 4 + c)] = vr[c];
    };

    load_regs(0);
    write_lds();
    __syncthreads();

    for (int kt = 0; kt < NT2; ++kt) {
        const int k0 = kt * 128;
        if (kt + 1 < NT2) load_regs(kt + 1);

        if (k0 <= q0w + 15) {  // causal skip for this wave's rows
            const bool a1 = (k0 + 64 <= q0w + 15);  // subtile-1 active
            f32x4 s[8];

            // ---- swapped QK^T, subtile 0 (kv k0..k0+63) ----
            __builtin_amdgcn_s_setprio(1);
#pragma unroll
            for (int nt = 0; nt < 4; ++nt) {
                bf16x8 kf0 = *(const bf16x8*)&Ks[0][swz8(nt * 16 + l15, lhi)];
                bf16x8 kf1 = *(const bf16x8*)&Ks[0][swz8(nt * 16 + l15, 4 + lhi)];
                f32x4 c = (f32x4){0.f, 0.f, 0.f, 0.f};
                c = mfma16(kf0, qf0, c);
                c = mfma16(kf1, qf1, c);
                s[nt] = c;
            }
            __builtin_amdgcn_s_setprio(0);

            // ---- subtile 1 (kv k0+64..k0+127) or -inf fill ----
            if (a1) {
                __builtin_amdgcn_s_setprio(1);
#pragma unroll
                for (int nt = 0; nt < 4; ++nt) {
                    bf16x8 kf0 = *(const bf16x8*)&Ks[1][swz8(nt * 16 + l15, lhi)];
                    bf16x8 kf1 = *(const bf16x8*)&Ks[1][swz8(nt * 16 + l15, 4 + lhi)];
                    f32x4 c = (f32x4){0.f, 0.f, 0.f, 0.f};
                    c = mfma16(kf0, qf0, c);
                    c = mfma16(kf1, qf1, c);
                    s[4 + nt] = c;
                }
                __builtin_amdgcn_s_setprio(0);
            } else {
#pragma unroll
                for (int nt = 0; nt < 4; ++nt)
                    s[4 + nt] = (f32x4){-3.0e38f, -3.0e38f, -3.0e38f, -3.0e38f};
            }

            // ---- causal masks (permuted kv indexing, per subtile) ----
            const int qg = q0w + l15;
            if (k0 + 63 > q0w) {
#pragma unroll
                for (int nt = 0; nt < 4; ++nt)
#pragma unroll
                    for (int r = 0; r < 4; ++r) {
                        int kg = k0 + (nt >> 1) * 32 + lhi * 8 + (nt & 1) * 4 + r;
                        if (kg > qg) s[nt][r] = -3.0e38f;
                    }
            }
            if (a1 && k0 + 127 > q0w) {
#pragma unroll
                for (int nt = 0; nt < 4; ++nt)
#pragma unroll
                    for (int r = 0; r < 4; ++r) {
                        int kg = k0 + 64 + (nt >> 1) * 32 + lhi * 8 +
                                 (nt & 1) * 4 + r;
                        if (kg > qg) s[4 + nt][r] = -3.0e38f;
                    }
            }

            // ---- row max over 128 kv: 31 fmax + 2 shfl ----
            float tm = s[0][0];
#pragma unroll
            for (int nt = 0; nt < 8; ++nt)
#pragma unroll
                for (int r = 0; r < 4; ++r) tm = fmaxf(tm, s[nt][r]);
            tm = fmaxf(tm, __shfl_xor(tm, 16));
            tm = fmaxf(tm, __shfl_xor(tm, 32));

            // ---- defer-max (T13) ----
            if (__any(tm - m_s > 8.0f)) {
                float mn = fmaxf(m_s, tm);
                float alpha = exp2f(m_s - mn);
                m_s = mn;
                l_s *= alpha;
                float aR[4];
#pragma unroll
                for (int r = 0; r < 4; ++r)
                    aR[r] = __shfl(alpha, (lane & 48) | (lhi * 4 + r));
#pragma unroll
                for (int dt = 0; dt < 4; ++dt)
#pragma unroll
                    for (int r = 0; r < 4; ++r) oacc[dt][r] *= aR[r];
            }

            // ---- P = exp2(s - m), row sum (inactive half underflows to 0) ----
            float rs = 0.f;
#pragma unroll
            for (int nt = 0; nt < 8; ++nt)
#pragma unroll
                for (int r = 0; r < 4; ++r) {
                    float pv = exp2f(s[nt][r] - m_s);  // log2e folded in Q
                    s[nt][r] = pv;
                    rs += pv;
                }
            rs += __shfl_xor(rs, 16);
            rs += __shfl_xor(rs, 32);
            l_s += rs;

            // ---- PV: A-frag lane-local, kc=0..3 from s[2kc],s[2kc+1] ----
#pragma unroll
            for (int kc = 0; kc < 4; ++kc) {
                if (kc < 2 || a1) {
                    union { unsigned int u[4]; bf16x8 v; } pf;
                    pf.u[0] = pkbf(s[2 * kc][0], s[2 * kc][1]);
                    pf.u[1] = pkbf(s[2 * kc][2], s[2 * kc][3]);
                    pf.u[2] = pkbf(s[2 * kc + 1][0], s[2 * kc + 1][1]);
                    pf.u[3] = pkbf(s[2 * kc + 1][2], s[2 * kc + 1][3]);
                    __builtin_amdgcn_s_setprio(1);
#pragma unroll
                    for (int dt = 0; dt < 4; ++dt) {
                        bf16x8 vf =
                            *(const bf16x8*)&Vt[vswz(dt * 16 + l15, kc * 4 + lhi)];
                        oacc[dt] = mfma16(pf.v, vf, oacc[dt]);
                    }
                    __builtin_amdgcn_s_setprio(0);
                }
            }
        }

        __syncthreads();  // all LDS reads of this tile done
        if (kt + 1 < NT2) {
            write_lds();
            __syncthreads();  // writes visible before next compute
        }
    }

    // ---- output: redistribute l to accumulator rows, store ----
    float lR[4];
#pragma unroll
    for (int r = 0; r < 4; ++r)
        lR[r] = __shfl(l_s, (lane & 48) | (lhi * 4 + r));
#pragma unroll
    for (int dt = 0; dt < 4; ++dt)
#pragma unroll
        for (int r = 0; r < 4; ++r) {
            int qg = q0w + lhi * 4 + r;
            int dg = dt * 16 + l15;
            float val = oacc[dt][r] / lR[r];
            O[(size_t)qg * DMODEL + h * DK + dg] = __float2bfloat16(val);
        }
}

extern "C" void kernel_launch(void* const* d_in, const int* in_sizes, int n_in,
                              void* d_out, int out_size, void* d_ws, size_t ws_size,
                              hipStream_t stream) {
    const float* x  = (const float*)d_in[0];
    const float* Wq = (const float*)d_in[1];
    const float* Wk = (const float*)d_in[2];
    const float* Wv = (const float*)d_in[3];
    const float* Wo = (const float*)d_in[4];
    float* out = (float*)d_out;

    bf16* q_ws = (bf16*)d_ws;                    // [H][S][64] bf16
    bf16* k_ws = q_ws + (size_t)S_LEN * DMODEL;  // [H][S][64] bf16
    bf16* v_ws = k_ws + (size_t)S_LEN * DMODEL;  // [H][64][S] bf16 (V^T)
    bf16* a_ws = v_ws + (size_t)S_LEN * DMODEL;  // [S][D] bf16

    dim3 gq(DMODEL / 128, S_LEN / 128, 3);
    qkv_proj<<<gq, 256, 0, stream>>>(x, Wq, Wk, Wv, q_ws, k_ws, v_ws);
    attn_kernel<<<1024, 256, 0, stream>>>(q_ws, k_ws, v_ws, a_ws);
    dim3 go(DMODEL / 128, S_LEN / 128);
    out_proj<<<go, 256, 0, stream>>>(a_ws, Wo, out);
}

// Round 18
// 176.233 us; speedup vs baseline: 1.4697x; 1.4697x over previous
//
#include <hip/hip_runtime.h>
#include <hip/hip_bf16.h>

#define S_LEN 4096
#define DMODEL 1024
#define NHEAD 16
#define DK 64

typedef __hip_bfloat16 bf16;
typedef __attribute__((ext_vector_type(8))) __bf16 bf16x8;
typedef __attribute__((ext_vector_type(4))) float f32x4;

__device__ __forceinline__ f32x4 mfma16(bf16x8 a, bf16x8 b, f32x4 c) {
    return __builtin_amdgcn_mfma_f32_16x16x32_bf16(a, b, c, 0, 0, 0);
}

// async global->LDS, 16B per lane. LDS dest is wave-uniform base + lane*16.
__device__ __forceinline__ void async16(const bf16* g, bf16* l) {
    __builtin_amdgcn_global_load_lds(
        (const __attribute__((address_space(1))) unsigned int*)g,
        (__attribute__((address_space(3))) unsigned int*)l, 16, 0, 0);
}

__device__ __forceinline__ bf16x8 cvt8(float4 a, float4 b) {
    bf16x8 r;
    r[0] = (__bf16)a.x; r[1] = (__bf16)a.y; r[2] = (__bf16)a.z; r[3] = (__bf16)a.w;
    r[4] = (__bf16)b.x; r[5] = (__bf16)b.y; r[6] = (__bf16)b.z; r[7] = (__bf16)b.w;
    return r;
}

// pack two f32 -> u32 of 2 bf16 (RNE)
__device__ __forceinline__ unsigned int pkbf(float lo, float hi) {
    unsigned short a = __bfloat16_as_ushort(__float2bfloat16(lo));
    unsigned short b = __bfloat16_as_ushort(__float2bfloat16(hi));
    return (unsigned int)a | ((unsigned int)b << 16);
}

// XOR-swizzled index into a [rows][64] bf16 tile (128B rows): 16B slot ^ (row&7).
__device__ __forceinline__ int swz8(int row, int col8) {  // col8 = col>>3
    return row * 64 + ((col8 ^ (row & 7)) << 3);
}

// K-row placement permutation: position p holds original kv with
// p = [b5 b2 b4 b3 b1 b0]. Makes swapped-QK^T leave each q-row's P values
// lane-local in PV A-frag order (kv = lhi*8 + j) -> zero-shuffle PV.
__device__ __forceinline__ int kperm(int kv) {
    return (kv & 0x23) | ((kv & 0x04) << 2) | ((kv & 0x18) >> 1);
}

// C[M][N] = A[M][K=1024] * B[N][K]^T, 128x128 tile, bf16 MFMA compute.
// MODE 0 (Q/K proj): A = f32 x, out = bf16 head-major [h][s][dk], scale folded
// MODE 1 (OUT proj): A = bf16 ws (global_load_lds), out = f32 row-major C[m][n]
// MODE 2 (V^T proj): A = f32 Wv, B = f32 x, out = bf16 [h=m>>6][d=m&63][s=n];
//                    block indices swapped (gridDim = (M-tiles, N-tiles) there)
template <int MODE>
__device__ __forceinline__ void gemm_body(const void* Ap, const float* B,
                                          void* Cp, float scale) {
    constexpr int K = DMODEL;
    __shared__ bf16 As[128 * 32];
    __shared__ bf16 Bs[128 * 32];

    const int t = threadIdx.x;
    const int lane = t & 63;
    const int l15 = lane & 15, lhi = lane >> 4;
    const int wave = t >> 6;
    const int wm = wave >> 1, wn = wave & 1;
    const int bm = (MODE == 2) ? blockIdx.x : blockIdx.y;
    const int bn = (MODE == 2) ? blockIdx.y : blockIdx.x;

    const int srow = t >> 2, scol = (t & 3) * 8;

    const float* gB = B + (size_t)(bn * 128 + srow) * K + scol;
    const float* gAf = (const float*)Ap + (size_t)(bm * 128 + srow) * K + scol;
    const bf16* gAb = (const bf16*)Ap + (size_t)(bm * 128 + srow) * K + scol;

    f32x4 acc[4][4];
#pragma unroll
    for (int i = 0; i < 4; ++i)
#pragma unroll
        for (int j = 0; j < 4; ++j) acc[i][j] = (f32x4){0.f, 0.f, 0.f, 0.f};

    for (int kt = 0; kt < K / 32; ++kt) {
        if (MODE != 1) {
            float4 a0 = *(const float4*)(gAf + kt * 32);
            float4 a1 = *(const float4*)(gAf + kt * 32 + 4);
            *(bf16x8*)&As[srow * 32 + scol] = cvt8(a0, a1);
            float4 a2 = *(const float4*)(gAf + kt * 32 + 64 * K);
            float4 a3 = *(const float4*)(gAf + kt * 32 + 64 * K + 4);
            *(bf16x8*)&As[2048 + srow * 32 + scol] = cvt8(a2, a3);
        } else {
            async16(gAb + kt * 32,          (bf16*)As + t * 8);
            async16(gAb + kt * 32 + 64 * K, (bf16*)As + 2048 + t * 8);
        }
        {
            float4 b0 = *(const float4*)(gB + kt * 32);
            float4 b1 = *(const float4*)(gB + kt * 32 + 4);
            *(bf16x8*)&Bs[srow * 32 + scol] = cvt8(b0, b1);
            float4 b2 = *(const float4*)(gB + kt * 32 + 64 * K);
            float4 b3 = *(const float4*)(gB + kt * 32 + 64 * K + 4);
            *(bf16x8*)&Bs[2048 + srow * 32 + scol] = cvt8(b2, b3);
        }
        __syncthreads();

        bf16x8 af[4], bv[4];
#pragma unroll
        for (int mt = 0; mt < 4; ++mt)
            af[mt] = *(const bf16x8*)&As[(wm * 64 + mt * 16 + l15) * 32 + lhi * 8];
#pragma unroll
        for (int nt = 0; nt < 4; ++nt)
            bv[nt] = *(const bf16x8*)&Bs[(wn * 64 + nt * 16 + l15) * 32 + lhi * 8];
#pragma unroll
        for (int mt = 0; mt < 4; ++mt)
#pragma unroll
            for (int nt = 0; nt < 4; ++nt)
                acc[mt][nt] = mfma16(af[mt], bv[nt], acc[mt][nt]);
        __syncthreads();
    }

#pragma unroll
    for (int mt = 0; mt < 4; ++mt)
#pragma unroll
        for (int nt = 0; nt < 4; ++nt)
#pragma unroll
            for (int r = 0; r < 4; ++r) {
                int m = bm * 128 + wm * 64 + mt * 16 + lhi * 4 + r;
                int n = bn * 128 + wn * 64 + nt * 16 + l15;
                float v = acc[mt][nt][r] * scale;
                if (MODE == 0)
                    ((bf16*)Cp)[((size_t)(n >> 6) * S_LEN + m) * DK + (n & 63)] =
                        __float2bfloat16(v);
                else if (MODE == 1)
                    ((float*)Cp)[(size_t)m * DMODEL + n] = v;
                else  // MODE 2: [h][d][s]
                    ((bf16*)Cp)[((size_t)(m >> 6) * DK + (m & 63)) * S_LEN + n] =
                        __float2bfloat16(v);
            }
}

// One launch, grid (8, 32, 3): z=0 Q, z=1 K (MODE 0), z=2 V^T (MODE 2,
// block indices swapped inside: x = M-tiles of DMODEL, y = N-tiles of S).
__global__ __launch_bounds__(256) void qkv_proj(const float* __restrict__ x,
                                                const float* __restrict__ Wq,
                                                const float* __restrict__ Wk,
                                                const float* __restrict__ Wv,
                                                bf16* __restrict__ q,
                                                bf16* __restrict__ k,
                                                bf16* __restrict__ vT) {
    const int z = blockIdx.z;
    if (z == 2) {
        gemm_body<2>(Wv, x, vT, 1.0f);
    } else {
        const float* B = (z == 0) ? Wq : Wk;
        bf16* out = (z == 0) ? q : k;
        float scale = (z == 0) ? 0.18033688011112042f : 1.0f;  // (1/sqrt64)*log2e
        gemm_body<0>(x, B, out, scale);
    }
}

__global__ __launch_bounds__(256) void out_proj(const bf16* __restrict__ A,
                                                const float* __restrict__ Wo,
                                                float* __restrict__ C) {
    gemm_body<1>(A, Wo, C, 1.0f);
}

// Flash attention, causal (best-measured configuration: 175.6us total,
// attn 104.5us). 256 threads = 4 waves x 16 q-rows (64-row q-tile).
// Grid 1024 = one unit (head, q-tile) per block. Unit mapping balances
// stride-256 residue classes (group g=b>>8 -> qt in {63-j, 32+j, 31-j, j}):
// any CU receiving blocks {c, c+256, c+512, c+768} gets exactly 130 KV-steps.
// SINGLE-buffer LDS (16KB/block); register prefetch (T14) hides HBM latency;
// cross-block overlap hides the extra barrier. V arrives PRE-TRANSPOSED
// [h][d][s]. K rows staged at PERMUTED LDS positions (kperm) so swapped-QK^T
// leaves P lane-local in PV A-frag order -> zero-shuffle PV. Swapped QK^T:
// lane holds full P-row for q=l15 -> scalar m/l, 2-shfl reductions. T13
// defer-max, T5 setprio.
__global__ __launch_bounds__(256) void attn_kernel(const bf16* __restrict__ Q,
                                                   const bf16* __restrict__ Kg,
                                                   const bf16* __restrict__ Vtg,
                                                   bf16* __restrict__ O) {
    __shared__ bf16 Ks[64 * 64];   // swizzled, K rows at kperm'd positions
    __shared__ bf16 Vt[64 * 64];   // swizzled [d][kv]

    const int b = blockIdx.x;
    const int t = threadIdx.x;
    const int lane = t & 63;
    const int l15 = lane & 15, lhi = lane >> 4;
    const int wave = t >> 6;

    // staging: 64 rows x 4 threads/row, 2 x 16B slots each (octet-clean banks;
    // kperm preserves bit0 so the K-write octet pattern stays conflict-free)
    const int srow = t >> 2, ssl = (t & 3) * 2;
    const int sprow = kperm(srow);

    // balanced unit mapping: stride-256 classes sum to 130 steps
    const int g = b >> 8, idx = b & 255;
    const int j = idx >> 4, h = idx & 15;
    const int qt = (g == 0) ? (63 - j) : (g == 1) ? (32 + j)
                 : (g == 2) ? (31 - j) : j;

    const bf16* qh = Q + (size_t)h * S_LEN * DK;
    const bf16* kh = Kg + (size_t)h * S_LEN * DK;
    const bf16* vh = Vtg + (size_t)h * DK * S_LEN;  // [d][s]

    const int q0w = qt * 64 + wave * 16;

    // Q B-fragments: row=q0w+l15, k chunks (scale+log2e folded in Q)
    bf16x8 qf0 = *(const bf16x8*)&qh[(size_t)(q0w + l15) * DK + lhi * 8];
    bf16x8 qf1 = *(const bf16x8*)&qh[(size_t)(q0w + l15) * DK + 32 + lhi * 8];

    float m_s = -3.0e38f, l_s = 0.f;  // scalar state for q = q0w + l15
    f32x4 oacc[4];
#pragma unroll
    for (int d = 0; d < 4; ++d) oacc[d] = (f32x4){0.f, 0.f, 0.f, 0.f};

    const int NT = qt + 1;
    uint4 kr0, kr1, vr0, vr1;

    auto load_regs = [&](int kt) {
        const int k0 = kt * 64;
        kr0 = *(const uint4*)&kh[(size_t)(k0 + srow) * DK + ssl * 8];
        kr1 = *(const uint4*)&kh[(size_t)(k0 + srow) * DK + ssl * 8 + 8];
        vr0 = *(const uint4*)&vh[(size_t)srow * S_LEN + k0 + ssl * 8];
        vr1 = *(const uint4*)&vh[(size_t)srow * S_LEN + k0 + ssl * 8 + 8];
    };
    auto write_lds = [&]() {
        *(uint4*)&Ks[swz8(sprow, ssl)] = kr0;       // K row srow -> pos kperm
        *(uint4*)&Ks[swz8(sprow, ssl + 1)] = kr1;
        *(uint4*)&Vt[swz8(srow, ssl)] = vr0;        // V^T unpermuted
        *(uint4*)&Vt[swz8(srow, ssl + 1)] = vr1;
    };

    load_regs(0);
    write_lds();
    __syncthreads();

    for (int kt = 0; kt < NT; ++kt) {
        const int k0 = kt * 64;
        if (kt + 1 < NT) load_regs(kt + 1);

        if (k0 <= q0w + 15) {  // causal skip for this wave's rows
            // ---- swapped QK^T over permuted K positions:
            // s[nt][r] = P[q=q0w+l15][kv = k0 + (nt>>1)*32 + lhi*8 + (nt&1)*4 + r]
            f32x4 s[4];
            __builtin_amdgcn_s_setprio(1);
#pragma unroll
            for (int nt = 0; nt < 4; ++nt) {
                bf16x8 kf0 = *(const bf16x8*)&Ks[swz8(nt * 16 + l15, lhi)];
                bf16x8 kf1 = *(const bf16x8*)&Ks[swz8(nt * 16 + l15, 4 + lhi)];
                f32x4 c = (f32x4){0.f, 0.f, 0.f, 0.f};
                c = mfma16(kf0, qf0, c);
                c = mfma16(kf1, qf1, c);
                s[nt] = c;
            }
            __builtin_amdgcn_s_setprio(0);

            // ---- causal mask (permuted kv indexing) ----
            if (k0 + 63 > q0w) {
                const int qg = q0w + l15;
#pragma unroll
                for (int nt = 0; nt < 4; ++nt)
#pragma unroll
                    for (int r = 0; r < 4; ++r) {
                        int kg = k0 + (nt >> 1) * 32 + lhi * 8 + (nt & 1) * 4 + r;
                        if (kg > qg) s[nt][r] = -3.0e38f;
                    }
            }

            // ---- row max: 15 fmax + 2 shfl ----
            float tm = s[0][0];
#pragma unroll
            for (int nt = 0; nt < 4; ++nt)
#pragma unroll
                for (int r = 0; r < 4; ++r) tm = fmaxf(tm, s[nt][r]);
            tm = fmaxf(tm, __shfl_xor(tm, 16));
            tm = fmaxf(tm, __shfl_xor(tm, 32));

            // ---- defer-max (T13) ----
            if (__any(tm - m_s > 8.0f)) {
                float mn = fmaxf(m_s, tm);
                float alpha = exp2f(m_s - mn);
                m_s = mn;
                l_s *= alpha;
                float aR[4];
#pragma unroll
                for (int r = 0; r < 4; ++r)
                    aR[r] = __shfl(alpha, (lane & 48) | (lhi * 4 + r));
#pragma unroll
                for (int dt = 0; dt < 4; ++dt)
#pragma unroll
                    for (int r = 0; r < 4; ++r) oacc[dt][r] *= aR[r];
            }

            // ---- P = exp2(s - m), row sum ----
            float rs = 0.f;
#pragma unroll
            for (int nt = 0; nt < 4; ++nt)
#pragma unroll
                for (int r = 0; r < 4; ++r) {
                    float pv = exp2f(s[nt][r] - m_s);  // log2e folded in Q
                    s[nt][r] = pv;
                    rs += pv;
                }
            rs += __shfl_xor(rs, 16);
            rs += __shfl_xor(rs, 32);
            l_s += rs;

            // ---- PV: A-frag is lane-local now -> pack and mfma ----
#pragma unroll
            for (int kc = 0; kc < 2; ++kc) {
                union { unsigned int u[4]; bf16x8 v; } pf;
                pf.u[0] = pkbf(s[2 * kc][0], s[2 * kc][1]);
                pf.u[1] = pkbf(s[2 * kc][2], s[2 * kc][3]);
                pf.u[2] = pkbf(s[2 * kc + 1][0], s[2 * kc + 1][1]);
                pf.u[3] = pkbf(s[2 * kc + 1][2], s[2 * kc + 1][3]);
                __builtin_amdgcn_s_setprio(1);
#pragma unroll
                for (int dt = 0; dt < 4; ++dt) {
                    bf16x8 vf =
                        *(const bf16x8*)&Vt[swz8(dt * 16 + l15, kc * 4 + lhi)];
                    oacc[dt] = mfma16(pf.v, vf, oacc[dt]);
                }
                __builtin_amdgcn_s_setprio(0);
            }
        }

        __syncthreads();  // all LDS reads of this tile done
        if (kt + 1 < NT) {
            write_lds();
            __syncthreads();  // writes visible before next compute
        }
    }

    // ---- output: redistribute l to accumulator rows, store ----
    float lR[4];
#pragma unroll
    for (int r = 0; r < 4; ++r)
        lR[r] = __shfl(l_s, (lane & 48) | (lhi * 4 + r));
#pragma unroll
    for (int dt = 0; dt < 4; ++dt)
#pragma unroll
        for (int r = 0; r < 4; ++r) {
            int qg = q0w + lhi * 4 + r;
            int dg = dt * 16 + l15;
            float val = oacc[dt][r] / lR[r];
            O[(size_t)qg * DMODEL + h * DK + dg] = __float2bfloat16(val);
        }
}

extern "C" void kernel_launch(void* const* d_in, const int* in_sizes, int n_in,
                              void* d_out, int out_size, void* d_ws, size_t ws_size,
                              hipStream_t stream) {
    const float* x  = (const float*)d_in[0];
    const float* Wq = (const float*)d_in[1];
    const float* Wk = (const float*)d_in[2];
    const float* Wv = (const float*)d_in[3];
    const float* Wo = (const float*)d_in[4];
    float* out = (float*)d_out;

    bf16* q_ws = (bf16*)d_ws;                    // [H][S][64] bf16
    bf16* k_ws = q_ws + (size_t)S_LEN * DMODEL;  // [H][S][64] bf16
    bf16* v_ws = k_ws + (size_t)S_LEN * DMODEL;  // [H][64][S] bf16 (V^T)
    bf16* a_ws = v_ws + (size_t)S_LEN * DMODEL;  // [S][D] bf16

    dim3 gq(DMODEL / 128, S_LEN / 128, 3);
    qkv_proj<<<gq, 256, 0, stream>>>(x, Wq, Wk, Wv, q_ws, k_ws, v_ws);
    attn_kernel<<<1024, 256, 0, stream>>>(q_ws, k_ws, v_ws, a_ws);
    dim3 go(DMODEL / 128, S_LEN / 128);
    out_proj<<<go, 256, 0, stream>>>(a_ws, Wo, out);
}

// Round 19
// 174.284 us; speedup vs baseline: 1.4861x; 1.0112x over previous
//
#include <hip/hip_runtime.h>
#include <hip/hip_bf16.h>

#define S_LEN 4096
#define DMODEL 1024
#define NHEAD 16
#define DK 64

typedef __hip_bfloat16 bf16;
typedef __attribute__((ext_vector_type(8))) __bf16 bf16x8;
typedef __attribute__((ext_vector_type(4))) float f32x4;

__device__ __forceinline__ f32x4 mfma16(bf16x8 a, bf16x8 b, f32x4 c) {
    return __builtin_amdgcn_mfma_f32_16x16x32_bf16(a, b, c, 0, 0, 0);
}

// async global->LDS, 16B per lane. LDS dest is wave-uniform base + lane*16.
__device__ __forceinline__ void async16(const bf16* g, bf16* l) {
    __builtin_amdgcn_global_load_lds(
        (const __attribute__((address_space(1))) unsigned int*)g,
        (__attribute__((address_space(3))) unsigned int*)l, 16, 0, 0);
}

__device__ __forceinline__ bf16x8 cvt8(float4 a, float4 b) {
    bf16x8 r;
    r[0] = (__bf16)a.x; r[1] = (__bf16)a.y; r[2] = (__bf16)a.z; r[3] = (__bf16)a.w;
    r[4] = (__bf16)b.x; r[5] = (__bf16)b.y; r[6] = (__bf16)b.z; r[7] = (__bf16)b.w;
    return r;
}

// pack two f32 -> u32 of 2 bf16 (RNE)
__device__ __forceinline__ unsigned int pkbf(float lo, float hi) {
    unsigned short a = __bfloat16_as_ushort(__float2bfloat16(lo));
    unsigned short b = __bfloat16_as_ushort(__float2bfloat16(hi));
    return (unsigned int)a | ((unsigned int)b << 16);
}

// XOR-swizzled index into a [rows][64] bf16 tile (128B rows): 16B slot ^ (row&7).
__device__ __forceinline__ int swz8(int row, int col8) {  // col8 = col>>3
    return row * 64 + ((col8 ^ (row & 7)) << 3);
}

// K-row placement permutation: position p holds original kv with
// p = [b5 b2 b4 b3 b1 b0]. Makes swapped-QK^T leave each q-row's P values
// lane-local in PV A-frag order (kv = lhi*8 + j) -> zero-shuffle PV.
__device__ __forceinline__ int kperm(int kv) {
    return (kv & 0x23) | ((kv & 0x04) << 2) | ((kv & 0x18) >> 1);
}

// C[M][N] = A[M][K=1024] * B[N][K]^T, 128x128 tile, bf16 MFMA compute.
// MODE 0 (Q/K proj): A = f32 x, out = bf16 head-major [h][s][dk], scale folded
// MODE 1 (OUT proj): A = bf16 ws (global_load_lds), out = f32 row-major C[m][n]
// MODE 2 (V^T proj): A = f32 Wv, B = f32 x, out = bf16 [h=m>>6][d=m&63][s=n];
//                    block indices swapped (gridDim = (M-tiles, N-tiles) there)
template <int MODE>
__device__ __forceinline__ void gemm_body(const void* Ap, const float* B,
                                          void* Cp, float scale) {
    constexpr int K = DMODEL;
    __shared__ bf16 As[128 * 32];
    __shared__ bf16 Bs[128 * 32];

    const int t = threadIdx.x;
    const int lane = t & 63;
    const int l15 = lane & 15, lhi = lane >> 4;
    const int wave = t >> 6;
    const int wm = wave >> 1, wn = wave & 1;
    const int bm = (MODE == 2) ? blockIdx.x : blockIdx.y;
    const int bn = (MODE == 2) ? blockIdx.y : blockIdx.x;

    const int srow = t >> 2, scol = (t & 3) * 8;

    const float* gB = B + (size_t)(bn * 128 + srow) * K + scol;
    const float* gAf = (const float*)Ap + (size_t)(bm * 128 + srow) * K + scol;
    const bf16* gAb = (const bf16*)Ap + (size_t)(bm * 128 + srow) * K + scol;

    f32x4 acc[4][4];
#pragma unroll
    for (int i = 0; i < 4; ++i)
#pragma unroll
        for (int j = 0; j < 4; ++j) acc[i][j] = (f32x4){0.f, 0.f, 0.f, 0.f};

    for (int kt = 0; kt < K / 32; ++kt) {
        if (MODE != 1) {
            float4 a0 = *(const float4*)(gAf + kt * 32);
            float4 a1 = *(const float4*)(gAf + kt * 32 + 4);
            *(bf16x8*)&As[srow * 32 + scol] = cvt8(a0, a1);
            float4 a2 = *(const float4*)(gAf + kt * 32 + 64 * K);
            float4 a3 = *(const float4*)(gAf + kt * 32 + 64 * K + 4);
            *(bf16x8*)&As[2048 + srow * 32 + scol] = cvt8(a2, a3);
        } else {
            async16(gAb + kt * 32,          (bf16*)As + t * 8);
            async16(gAb + kt * 32 + 64 * K, (bf16*)As + 2048 + t * 8);
        }
        {
            float4 b0 = *(const float4*)(gB + kt * 32);
            float4 b1 = *(const float4*)(gB + kt * 32 + 4);
            *(bf16x8*)&Bs[srow * 32 + scol] = cvt8(b0, b1);
            float4 b2 = *(const float4*)(gB + kt * 32 + 64 * K);
            float4 b3 = *(const float4*)(gB + kt * 32 + 64 * K + 4);
            *(bf16x8*)&Bs[2048 + srow * 32 + scol] = cvt8(b2, b3);
        }
        __syncthreads();

        bf16x8 af[4], bv[4];
#pragma unroll
        for (int mt = 0; mt < 4; ++mt)
            af[mt] = *(const bf16x8*)&As[(wm * 64 + mt * 16 + l15) * 32 + lhi * 8];
#pragma unroll
        for (int nt = 0; nt < 4; ++nt)
            bv[nt] = *(const bf16x8*)&Bs[(wn * 64 + nt * 16 + l15) * 32 + lhi * 8];
#pragma unroll
        for (int mt = 0; mt < 4; ++mt)
#pragma unroll
            for (int nt = 0; nt < 4; ++nt)
                acc[mt][nt] = mfma16(af[mt], bv[nt], acc[mt][nt]);
        __syncthreads();
    }

#pragma unroll
    for (int mt = 0; mt < 4; ++mt)
#pragma unroll
        for (int nt = 0; nt < 4; ++nt)
#pragma unroll
            for (int r = 0; r < 4; ++r) {
                int m = bm * 128 + wm * 64 + mt * 16 + lhi * 4 + r;
                int n = bn * 128 + wn * 64 + nt * 16 + l15;
                float v = acc[mt][nt][r] * scale;
                if (MODE == 0)
                    ((bf16*)Cp)[((size_t)(n >> 6) * S_LEN + m) * DK + (n & 63)] =
                        __float2bfloat16(v);
                else if (MODE == 1)
                    ((float*)Cp)[(size_t)m * DMODEL + n] = v;
                else  // MODE 2: [h][d][s]
                    ((bf16*)Cp)[((size_t)(m >> 6) * DK + (m & 63)) * S_LEN + n] =
                        __float2bfloat16(v);
            }
}

// One launch, grid (8, 32, 3): z=0 Q, z=1 K (MODE 0), z=2 V^T (MODE 2,
// block indices swapped inside: x = M-tiles of DMODEL, y = N-tiles of S).
__global__ __launch_bounds__(256) void qkv_proj(const float* __restrict__ x,
                                                const float* __restrict__ Wq,
                                                const float* __restrict__ Wk,
                                                const float* __restrict__ Wv,
                                                bf16* __restrict__ q,
                                                bf16* __restrict__ k,
                                                bf16* __restrict__ vT) {
    const int z = blockIdx.z;
    if (z == 2) {
        gemm_body<2>(Wv, x, vT, 1.0f);
    } else {
        const float* B = (z == 0) ? Wq : Wk;
        bf16* out = (z == 0) ? q : k;
        float scale = (z == 0) ? 0.18033688011112042f : 1.0f;  // (1/sqrt64)*log2e
        gemm_body<0>(x, B, out, scale);
    }
}

__global__ __launch_bounds__(256) void out_proj(const bf16* __restrict__ A,
                                                const float* __restrict__ Wo,
                                                float* __restrict__ C) {
    gemm_body<1>(A, Wo, C, 1.0f);
}

// Flash attention, causal. KVBLK=128 STAGING with SEQUENTIAL 64-kv subtile
// compute: both subtiles staged in one burst (one barrier pair per 128 kv =
// half of R12's), but each subtile runs the exact R12 inner body so only
// s[4] is live at a time (fixes the R16/R17 spill: s[8] live across
// conditionals went to scratch, 478MB WRITE_SIZE). Prefetch in NAMED uint4
// scalars (rule #20). 256 threads = 4 waves x 16 q-rows. Grid 1024, balanced
// mapping (stride-256 classes sum to exactly 66 128-steps, both parities).
// V PRE-TRANSPOSED [h][d][s], stored as two [64][64] subtiles. K rows at
// kperm'd positions -> zero-shuffle PV. Scalar m/l, 2-shfl reductions, T13
// defer-max, T5 setprio, T14 register prefetch.
__global__ __launch_bounds__(256) void attn_kernel(const bf16* __restrict__ Q,
                                                   const bf16* __restrict__ Kg,
                                                   const bf16* __restrict__ Vtg,
                                                   bf16* __restrict__ O) {
    __shared__ bf16 Ks[2][64 * 64];   // [kv-subtile][swizzled kperm'd rows]
    __shared__ bf16 Vt[2][64 * 64];   // [kv-subtile][swizzled [d][kv64]]

    const int b = blockIdx.x;
    const int t = threadIdx.x;
    const int lane = t & 63;
    const int l15 = lane & 15, lhi = lane >> 4;
    const int wave = t >> 6;

    // K staging: 128 rows x 2 threads/row, 4 x 16B slots each
    const int srowK = t >> 1, halfK = t & 1;
    const int subK = srowK >> 6;
    const int kposK = kperm(srowK & 63);
    // V staging: 64 d-rows x 4 threads/row, 4 x 16B slots (qv pair -> subtile)
    const int srowV = t >> 2, qv = t & 3;
    const int vsub = qv >> 1, vcol = (qv & 1) * 4;

    // balanced unit mapping: stride-256 classes sum to 66 128-steps
    const int g = b >> 8, idx = b & 255;
    const int j = idx >> 4, h = idx & 15;
    const int qt = (g == 0) ? (63 - j) : (g == 1) ? (32 + j)
                 : (g == 2) ? (31 - j) : j;

    const bf16* qh = Q + (size_t)h * S_LEN * DK;
    const bf16* kh = Kg + (size_t)h * S_LEN * DK;
    const bf16* vh = Vtg + (size_t)h * DK * S_LEN;  // [d][s]

    const int q0w = qt * 64 + wave * 16;

    // Q B-fragments: row=q0w+l15, k chunks (scale+log2e folded in Q)
    bf16x8 qf0 = *(const bf16x8*)&qh[(size_t)(q0w + l15) * DK + lhi * 8];
    bf16x8 qf1 = *(const bf16x8*)&qh[(size_t)(q0w + l15) * DK + 32 + lhi * 8];

    float m_s = -3.0e38f, l_s = 0.f;  // scalar state for q = q0w + l15
    f32x4 oacc[4];
#pragma unroll
    for (int d = 0; d < 4; ++d) oacc[d] = (f32x4){0.f, 0.f, 0.f, 0.f};

    const int NT2 = (qt + 2) >> 1;  // ceil((qt+1)/2) 128-wide staging steps
    uint4 kr0, kr1, kr2, kr3, vr0, vr1, vr2, vr3;

    auto load_regs = [&](int kt) {
        const int k0 = kt * 128;
        const bf16* kp = &kh[(size_t)(k0 + srowK) * DK + halfK * 32];
        kr0 = *(const uint4*)(kp);
        kr1 = *(const uint4*)(kp + 8);
        kr2 = *(const uint4*)(kp + 16);
        kr3 = *(const uint4*)(kp + 24);
        const bf16* vp = &vh[(size_t)srowV * S_LEN + k0 + qv * 32];
        vr0 = *(const uint4*)(vp);
        vr1 = *(const uint4*)(vp + 8);
        vr2 = *(const uint4*)(vp + 16);
        vr3 = *(const uint4*)(vp + 24);
    };
    auto write_lds = [&]() {
        *(uint4*)&Ks[subK][swz8(kposK, halfK * 4 + 0)] = kr0;
        *(uint4*)&Ks[subK][swz8(kposK, halfK * 4 + 1)] = kr1;
        *(uint4*)&Ks[subK][swz8(kposK, halfK * 4 + 2)] = kr2;
        *(uint4*)&Ks[subK][swz8(kposK, halfK * 4 + 3)] = kr3;
        *(uint4*)&Vt[vsub][swz8(srowV, vcol + 0)] = vr0;
        *(uint4*)&Vt[vsub][swz8(srowV, vcol + 1)] = vr1;
        *(uint4*)&Vt[vsub][swz8(srowV, vcol + 2)] = vr2;
        *(uint4*)&Vt[vsub][swz8(srowV, vcol + 3)] = vr3;
    };

    load_regs(0);
    write_lds();
    __syncthreads();

    for (int kt = 0; kt < NT2; ++kt) {
        if (kt + 1 < NT2) load_regs(kt + 1);

#pragma unroll
        for (int sub = 0; sub < 2; ++sub) {
            const int k0 = kt * 128 + sub * 64;
            if (k0 <= q0w + 15) {  // causal skip for this wave's rows
                // ---- swapped QK^T over permuted K positions (R12 body):
                // s[nt][r] = P[q=q0w+l15][kv = k0+(nt>>1)*32+lhi*8+(nt&1)*4+r]
                f32x4 s[4];
                __builtin_amdgcn_s_setprio(1);
#pragma unroll
                for (int nt = 0; nt < 4; ++nt) {
                    bf16x8 kf0 = *(const bf16x8*)&Ks[sub][swz8(nt * 16 + l15, lhi)];
                    bf16x8 kf1 =
                        *(const bf16x8*)&Ks[sub][swz8(nt * 16 + l15, 4 + lhi)];
                    f32x4 c = (f32x4){0.f, 0.f, 0.f, 0.f};
                    c = mfma16(kf0, qf0, c);
                    c = mfma16(kf1, qf1, c);
                    s[nt] = c;
                }
                __builtin_amdgcn_s_setprio(0);

                // ---- causal mask (permuted kv indexing) ----
                if (k0 + 63 > q0w) {
                    const int qg = q0w + l15;
#pragma unroll
                    for (int nt = 0; nt < 4; ++nt)
#pragma unroll
                        for (int r = 0; r < 4; ++r) {
                            int kg = k0 + (nt >> 1) * 32 + lhi * 8 +
                                     (nt & 1) * 4 + r;
                            if (kg > qg) s[nt][r] = -3.0e38f;
                        }
                }

                // ---- row max: 15 fmax + 2 shfl ----
                float tm = s[0][0];
#pragma unroll
                for (int nt = 0; nt < 4; ++nt)
#pragma unroll
                    for (int r = 0; r < 4; ++r) tm = fmaxf(tm, s[nt][r]);
                tm = fmaxf(tm, __shfl_xor(tm, 16));
                tm = fmaxf(tm, __shfl_xor(tm, 32));

                // ---- defer-max (T13) ----
                if (__any(tm - m_s > 8.0f)) {
                    float mn = fmaxf(m_s, tm);
                    float alpha = exp2f(m_s - mn);
                    m_s = mn;
                    l_s *= alpha;
                    float aR[4];
#pragma unroll
                    for (int r = 0; r < 4; ++r)
                        aR[r] = __shfl(alpha, (lane & 48) | (lhi * 4 + r));
#pragma unroll
                    for (int dt = 0; dt < 4; ++dt)
#pragma unroll
                        for (int r = 0; r < 4; ++r) oacc[dt][r] *= aR[r];
                }

                // ---- P = exp2(s - m), row sum ----
                float rs = 0.f;
#pragma unroll
                for (int nt = 0; nt < 4; ++nt)
#pragma unroll
                    for (int r = 0; r < 4; ++r) {
                        float pv = exp2f(s[nt][r] - m_s);  // log2e folded in Q
                        s[nt][r] = pv;
                        rs += pv;
                    }
                rs += __shfl_xor(rs, 16);
                rs += __shfl_xor(rs, 32);
                l_s += rs;

                // ---- PV: A-frag lane-local -> pack and mfma ----
#pragma unroll
                for (int kc = 0; kc < 2; ++kc) {
                    union { unsigned int u[4]; bf16x8 v; } pf;
                    pf.u[0] = pkbf(s[2 * kc][0], s[2 * kc][1]);
                    pf.u[1] = pkbf(s[2 * kc][2], s[2 * kc][3]);
                    pf.u[2] = pkbf(s[2 * kc + 1][0], s[2 * kc + 1][1]);
                    pf.u[3] = pkbf(s[2 * kc + 1][2], s[2 * kc + 1][3]);
                    __builtin_amdgcn_s_setprio(1);
#pragma unroll
                    for (int dt = 0; dt < 4; ++dt) {
                        bf16x8 vf = *(const bf16x8*)
                            &Vt[sub][swz8(dt * 16 + l15, kc * 4 + lhi)];
                        oacc[dt] = mfma16(pf.v, vf, oacc[dt]);
                    }
                    __builtin_amdgcn_s_setprio(0);
                }
            }
        }

        __syncthreads();  // all LDS reads of this 128-tile done
        if (kt + 1 < NT2) {
            write_lds();
            __syncthreads();  // writes visible before next compute
        }
    }

    // ---- output: redistribute l to accumulator rows, store ----
    float lR[4];
#pragma unroll
    for (int r = 0; r < 4; ++r)
        lR[r] = __shfl(l_s, (lane & 48) | (lhi * 4 + r));
#pragma unroll
    for (int dt = 0; dt < 4; ++dt)
#pragma unroll
        for (int r = 0; r < 4; ++r) {
            int qg = q0w + lhi * 4 + r;
            int dg = dt * 16 + l15;
            float val = oacc[dt][r] / lR[r];
            O[(size_t)qg * DMODEL + h * DK + dg] = __float2bfloat16(val);
        }
}

extern "C" void kernel_launch(void* const* d_in, const int* in_sizes, int n_in,
                              void* d_out, int out_size, void* d_ws, size_t ws_size,
                              hipStream_t stream) {
    const float* x  = (const float*)d_in[0];
    const float* Wq = (const float*)d_in[1];
    const float* Wk = (const float*)d_in[2];
    const float* Wv = (const float*)d_in[3];
    const float* Wo = (const float*)d_in[4];
    float* out = (float*)d_out;

    bf16* q_ws = (bf16*)d_ws;                    // [H][S][64] bf16
    bf16* k_ws = q_ws + (size_t)S_LEN * DMODEL;  // [H][S][64] bf16
    bf16* v_ws = k_ws + (size_t)S_LEN * DMODEL;  // [H][64][S] bf16 (V^T)
    bf16* a_ws = v_ws + (size_t)S_LEN * DMODEL;  // [S][D] bf16

    dim3 gq(DMODEL / 128, S_LEN / 128, 3);
    qkv_proj<<<gq, 256, 0, stream>>>(x, Wq, Wk, Wv, q_ws, k_ws, v_ws);
    attn_kernel<<<1024, 256, 0, stream>>>(q_ws, k_ws, v_ws, a_ws);
    dim3 go(DMODEL / 128, S_LEN / 128);
    out_proj<<<go, 256, 0, stream>>>(a_ws, Wo, out);
}

// Round 20
// 171.287 us; speedup vs baseline: 1.5121x; 1.0175x over previous
//
#include <hip/hip_runtime.h>
#include <hip/hip_bf16.h>

#define S_LEN 4096
#define DMODEL 1024
#define NHEAD 16
#define DK 64

typedef __hip_bfloat16 bf16;
typedef __attribute__((ext_vector_type(8))) __bf16 bf16x8;
typedef __attribute__((ext_vector_type(4))) float f32x4;

__device__ __forceinline__ f32x4 mfma16(bf16x8 a, bf16x8 b, f32x4 c) {
    return __builtin_amdgcn_mfma_f32_16x16x32_bf16(a, b, c, 0, 0, 0);
}

// async global->LDS, 16B per lane. LDS dest is wave-uniform base + lane*16.
__device__ __forceinline__ void async16(const bf16* g, bf16* l) {
    __builtin_amdgcn_global_load_lds(
        (const __attribute__((address_space(1))) unsigned int*)g,
        (__attribute__((address_space(3))) unsigned int*)l, 16, 0, 0);
}

__device__ __forceinline__ bf16x8 cvt8(float4 a, float4 b) {
    bf16x8 r;
    r[0] = (__bf16)a.x; r[1] = (__bf16)a.y; r[2] = (__bf16)a.z; r[3] = (__bf16)a.w;
    r[4] = (__bf16)b.x; r[5] = (__bf16)b.y; r[6] = (__bf16)b.z; r[7] = (__bf16)b.w;
    return r;
}

// pack two f32 -> u32 of 2 bf16 (RNE)
__device__ __forceinline__ unsigned int pkbf(float lo, float hi) {
    unsigned short a = __bfloat16_as_ushort(__float2bfloat16(lo));
    unsigned short b = __bfloat16_as_ushort(__float2bfloat16(hi));
    return (unsigned int)a | ((unsigned int)b << 16);
}

// XOR-swizzled index into a [rows][64] bf16 tile (128B rows): 16B slot ^ (row&7).
__device__ __forceinline__ int swz8(int row, int col8) {  // col8 = col>>3
    return row * 64 + ((col8 ^ (row & 7)) << 3);
}

// K-row placement permutation: position p holds original kv with
// p = [b5 b2 b4 b3 b1 b0]. Makes swapped-QK^T leave each q-row's P values
// lane-local in PV A-frag order (kv = lhi*8 + j) -> zero-shuffle PV.
__device__ __forceinline__ int kperm(int kv) {
    return (kv & 0x23) | ((kv & 0x04) << 2) | ((kv & 0x18) >> 1);
}

// XCD-aware remap (T1): 256 linear blocks -> (ybm in 0..31, xbn in 0..7) such
// that the 8 blocks sharing ybm have identical lin%8 -> land on one XCD under
// round-robin dispatch -> the shared 2MB A-row-panel stays L2-resident.
// Bijective: lin = ((ybm&3)*8 + xbn)*8 + (ybm>>2).
__device__ __forceinline__ void xcd_remap(int lin, int& ybm, int& xbn) {
    const int q = lin >> 3, r = lin & 7;
    ybm = r * 4 + (q >> 3);
    xbn = q & 7;
}

// C[M][N] = A[M][K=1024] * B[N][K]^T, 128x128 tile, bf16 MFMA compute.
// MODE 0 (Q/K proj): A = f32 x, out = bf16 head-major [h][s][dk], scale folded
// MODE 1 (OUT proj): A = bf16 ws (global_load_lds), out = f32 row-major C[m][n]
// MODE 2 (V^T proj): A = f32 Wv, B = f32 x, out = bf16 [h=m>>6][d=m&63][s=n]
// (bm, bn) supplied by the caller (XCD-remapped).
template <int MODE>
__device__ __forceinline__ void gemm_body(const void* Ap, const float* B,
                                          void* Cp, float scale, int bm, int bn) {
    constexpr int K = DMODEL;
    __shared__ bf16 As[128 * 32];
    __shared__ bf16 Bs[128 * 32];

    const int t = threadIdx.x;
    const int lane = t & 63;
    const int l15 = lane & 15, lhi = lane >> 4;
    const int wave = t >> 6;
    const int wm = wave >> 1, wn = wave & 1;

    const int srow = t >> 2, scol = (t & 3) * 8;

    const float* gB = B + (size_t)(bn * 128 + srow) * K + scol;
    const float* gAf = (const float*)Ap + (size_t)(bm * 128 + srow) * K + scol;
    const bf16* gAb = (const bf16*)Ap + (size_t)(bm * 128 + srow) * K + scol;

    f32x4 acc[4][4];
#pragma unroll
    for (int i = 0; i < 4; ++i)
#pragma unroll
        for (int j = 0; j < 4; ++j) acc[i][j] = (f32x4){0.f, 0.f, 0.f, 0.f};

    for (int kt = 0; kt < K / 32; ++kt) {
        if (MODE != 1) {
            float4 a0 = *(const float4*)(gAf + kt * 32);
            float4 a1 = *(const float4*)(gAf + kt * 32 + 4);
            *(bf16x8*)&As[srow * 32 + scol] = cvt8(a0, a1);
            float4 a2 = *(const float4*)(gAf + kt * 32 + 64 * K);
            float4 a3 = *(const float4*)(gAf + kt * 32 + 64 * K + 4);
            *(bf16x8*)&As[2048 + srow * 32 + scol] = cvt8(a2, a3);
        } else {
            async16(gAb + kt * 32,          (bf16*)As + t * 8);
            async16(gAb + kt * 32 + 64 * K, (bf16*)As + 2048 + t * 8);
        }
        {
            float4 b0 = *(const float4*)(gB + kt * 32);
            float4 b1 = *(const float4*)(gB + kt * 32 + 4);
            *(bf16x8*)&Bs[srow * 32 + scol] = cvt8(b0, b1);
            float4 b2 = *(const float4*)(gB + kt * 32 + 64 * K);
            float4 b3 = *(const float4*)(gB + kt * 32 + 64 * K + 4);
            *(bf16x8*)&Bs[2048 + srow * 32 + scol] = cvt8(b2, b3);
        }
        __syncthreads();

        bf16x8 af[4], bv[4];
#pragma unroll
        for (int mt = 0; mt < 4; ++mt)
            af[mt] = *(const bf16x8*)&As[(wm * 64 + mt * 16 + l15) * 32 + lhi * 8];
#pragma unroll
        for (int nt = 0; nt < 4; ++nt)
            bv[nt] = *(const bf16x8*)&Bs[(wn * 64 + nt * 16 + l15) * 32 + lhi * 8];
#pragma unroll
        for (int mt = 0; mt < 4; ++mt)
#pragma unroll
            for (int nt = 0; nt < 4; ++nt)
                acc[mt][nt] = mfma16(af[mt], bv[nt], acc[mt][nt]);
        __syncthreads();
    }

#pragma unroll
    for (int mt = 0; mt < 4; ++mt)
#pragma unroll
        for (int nt = 0; nt < 4; ++nt)
#pragma unroll
            for (int r = 0; r < 4; ++r) {
                int m = bm * 128 + wm * 64 + mt * 16 + lhi * 4 + r;
                int n = bn * 128 + wn * 64 + nt * 16 + l15;
                float v = acc[mt][nt][r] * scale;
                if (MODE == 0)
                    ((bf16*)Cp)[((size_t)(n >> 6) * S_LEN + m) * DK + (n & 63)] =
                        __float2bfloat16(v);
                else if (MODE == 1)
                    ((float*)Cp)[(size_t)m * DMODEL + n] = v;
                else  // MODE 2: [h][d][s]
                    ((bf16*)Cp)[((size_t)(m >> 6) * DK + (m & 63)) * S_LEN + n] =
                        __float2bfloat16(v);
            }
}

// One launch, grid (256, 1, 3): z=0 Q, z=1 K (MODE 0: bm=ybm M-tiles of S,
// bn=xbn N-tiles of DMODEL), z=2 V^T (MODE 2: bm=xbn DMODEL tiles, bn=ybm
// S tiles). XCD remap keeps each shared operand panel on one XCD's L2.
__global__ __launch_bounds__(256) void qkv_proj(const float* __restrict__ x,
                                                const float* __restrict__ Wq,
                                                const float* __restrict__ Wk,
                                                const float* __restrict__ Wv,
                                                bf16* __restrict__ q,
                                                bf16* __restrict__ k,
                                                bf16* __restrict__ vT) {
    int ybm, xbn;
    xcd_remap(blockIdx.x, ybm, xbn);
    const int z = blockIdx.z;
    if (z == 2) {
        gemm_body<2>(Wv, x, vT, 1.0f, xbn, ybm);
    } else {
        const float* B = (z == 0) ? Wq : Wk;
        bf16* out = (z == 0) ? q : k;
        float scale = (z == 0) ? 0.18033688011112042f : 1.0f;  // (1/sqrt64)*log2e
        gemm_body<0>(x, B, out, scale, ybm, xbn);
    }
}

__global__ __launch_bounds__(256) void out_proj(const bf16* __restrict__ A,
                                                const float* __restrict__ Wo,
                                                float* __restrict__ C) {
    int ybm, xbn;
    xcd_remap(blockIdx.x, ybm, xbn);
    gemm_body<1>(A, Wo, C, 1.0f, ybm, xbn);
}

// Flash attention, causal. KVBLK=128 STAGING with SEQUENTIAL 64-kv subtile
// compute (best measured: 174.3us total, attn ~105us): both subtiles staged
// in one burst (one barrier pair per 128 kv), each subtile runs the proven
// R12 inner body so only s[4] is live (no spill: VGPR 68, WRITE_SIZE 8KB).
// Prefetch in NAMED uint4 scalars. 256 threads = 4 waves x 16 q-rows.
// Grid 1024, balanced mapping (stride-256 classes sum to 66 128-steps).
// V PRE-TRANSPOSED [h][d][s] as two [64][64] subtiles. K rows at kperm'd
// positions -> zero-shuffle PV. Scalar m/l, 2-shfl reductions, T13 defer-max,
// T5 setprio, T14 register prefetch.
__global__ __launch_bounds__(256) void attn_kernel(const bf16* __restrict__ Q,
                                                   const bf16* __restrict__ Kg,
                                                   const bf16* __restrict__ Vtg,
                                                   bf16* __restrict__ O) {
    __shared__ bf16 Ks[2][64 * 64];   // [kv-subtile][swizzled kperm'd rows]
    __shared__ bf16 Vt[2][64 * 64];   // [kv-subtile][swizzled [d][kv64]]

    const int b = blockIdx.x;
    const int t = threadIdx.x;
    const int lane = t & 63;
    const int l15 = lane & 15, lhi = lane >> 4;
    const int wave = t >> 6;

    // K staging: 128 rows x 2 threads/row, 4 x 16B slots each
    const int srowK = t >> 1, halfK = t & 1;
    const int subK = srowK >> 6;
    const int kposK = kperm(srowK & 63);
    // V staging: 64 d-rows x 4 threads/row, 4 x 16B slots (qv pair -> subtile)
    const int srowV = t >> 2, qv = t & 3;
    const int vsub = qv >> 1, vcol = (qv & 1) * 4;

    // balanced unit mapping: stride-256 classes sum to 66 128-steps
    const int g = b >> 8, idx = b & 255;
    const int j = idx >> 4, h = idx & 15;
    const int qt = (g == 0) ? (63 - j) : (g == 1) ? (32 + j)
                 : (g == 2) ? (31 - j) : j;

    const bf16* qh = Q + (size_t)h * S_LEN * DK;
    const bf16* kh = Kg + (size_t)h * S_LEN * DK;
    const bf16* vh = Vtg + (size_t)h * DK * S_LEN;  // [d][s]

    const int q0w = qt * 64 + wave * 16;

    // Q B-fragments: row=q0w+l15, k chunks (scale+log2e folded in Q)
    bf16x8 qf0 = *(const bf16x8*)&qh[(size_t)(q0w + l15) * DK + lhi * 8];
    bf16x8 qf1 = *(const bf16x8*)&qh[(size_t)(q0w + l15) * DK + 32 + lhi * 8];

    float m_s = -3.0e38f, l_s = 0.f;  // scalar state for q = q0w + l15
    f32x4 oacc[4];
#pragma unroll
    for (int d = 0; d < 4; ++d) oacc[d] = (f32x4){0.f, 0.f, 0.f, 0.f};

    const int NT2 = (qt + 2) >> 1;  // ceil((qt+1)/2) 128-wide staging steps
    uint4 kr0, kr1, kr2, kr3, vr0, vr1, vr2, vr3;

    auto load_regs = [&](int kt) {
        const int k0 = kt * 128;
        const bf16* kp = &kh[(size_t)(k0 + srowK) * DK + halfK * 32];
        kr0 = *(const uint4*)(kp);
        kr1 = *(const uint4*)(kp + 8);
        kr2 = *(const uint4*)(kp + 16);
        kr3 = *(const uint4*)(kp + 24);
        const bf16* vp = &vh[(size_t)srowV * S_LEN + k0 + qv * 32];
        vr0 = *(const uint4*)(vp);
        vr1 = *(const uint4*)(vp + 8);
        vr2 = *(const uint4*)(vp + 16);
        vr3 = *(const uint4*)(vp + 24);
    };
    auto write_lds = [&]() {
        *(uint4*)&Ks[subK][swz8(kposK, halfK * 4 + 0)] = kr0;
        *(uint4*)&Ks[subK][swz8(kposK, halfK * 4 + 1)] = kr1;
        *(uint4*)&Ks[subK][swz8(kposK, halfK * 4 + 2)] = kr2;
        *(uint4*)&Ks[subK][swz8(kposK, halfK * 4 + 3)] = kr3;
        *(uint4*)&Vt[vsub][swz8(srowV, vcol + 0)] = vr0;
        *(uint4*)&Vt[vsub][swz8(srowV, vcol + 1)] = vr1;
        *(uint4*)&Vt[vsub][swz8(srowV, vcol + 2)] = vr2;
        *(uint4*)&Vt[vsub][swz8(srowV, vcol + 3)] = vr3;
    };

    load_regs(0);
    write_lds();
    __syncthreads();

    for (int kt = 0; kt < NT2; ++kt) {
        if (kt + 1 < NT2) load_regs(kt + 1);

#pragma unroll
        for (int sub = 0; sub < 2; ++sub) {
            const int k0 = kt * 128 + sub * 64;
            if (k0 <= q0w + 15) {  // causal skip for this wave's rows
                // ---- swapped QK^T over permuted K positions (R12 body):
                // s[nt][r] = P[q=q0w+l15][kv = k0+(nt>>1)*32+lhi*8+(nt&1)*4+r]
                f32x4 s[4];
                __builtin_amdgcn_s_setprio(1);
#pragma unroll
                for (int nt = 0; nt < 4; ++nt) {
                    bf16x8 kf0 = *(const bf16x8*)&Ks[sub][swz8(nt * 16 + l15, lhi)];
                    bf16x8 kf1 =
                        *(const bf16x8*)&Ks[sub][swz8(nt * 16 + l15, 4 + lhi)];
                    f32x4 c = (f32x4){0.f, 0.f, 0.f, 0.f};
                    c = mfma16(kf0, qf0, c);
                    c = mfma16(kf1, qf1, c);
                    s[nt] = c;
                }
                __builtin_amdgcn_s_setprio(0);

                // ---- causal mask (permuted kv indexing) ----
                if (k0 + 63 > q0w) {
                    const int qg = q0w + l15;
#pragma unroll
                    for (int nt = 0; nt < 4; ++nt)
#pragma unroll
                        for (int r = 0; r < 4; ++r) {
                            int kg = k0 + (nt >> 1) * 32 + lhi * 8 +
                                     (nt & 1) * 4 + r;
                            if (kg > qg) s[nt][r] = -3.0e38f;
                        }
                }

                // ---- row max: 15 fmax + 2 shfl ----
                float tm = s[0][0];
#pragma unroll
                for (int nt = 0; nt < 4; ++nt)
#pragma unroll
                    for (int r = 0; r < 4; ++r) tm = fmaxf(tm, s[nt][r]);
                tm = fmaxf(tm, __shfl_xor(tm, 16));
                tm = fmaxf(tm, __shfl_xor(tm, 32));

                // ---- defer-max (T13) ----
                if (__any(tm - m_s > 8.0f)) {
                    float mn = fmaxf(m_s, tm);
                    float alpha = exp2f(m_s - mn);
                    m_s = mn;
                    l_s *= alpha;
                    float aR[4];
#pragma unroll
                    for (int r = 0; r < 4; ++r)
                        aR[r] = __shfl(alpha, (lane & 48) | (lhi * 4 + r));
#pragma unroll
                    for (int dt = 0; dt < 4; ++dt)
#pragma unroll
                        for (int r = 0; r < 4; ++r) oacc[dt][r] *= aR[r];
                }

                // ---- P = exp2(s - m), row sum ----
                float rs = 0.f;
#pragma unroll
                for (int nt = 0; nt < 4; ++nt)
#pragma unroll
                    for (int r = 0; r < 4; ++r) {
                        float pv = exp2f(s[nt][r] - m_s);  // log2e folded in Q
                        s[nt][r] = pv;
                        rs += pv;
                    }
                rs += __shfl_xor(rs, 16);
                rs += __shfl_xor(rs, 32);
                l_s += rs;

                // ---- PV: A-frag lane-local -> pack and mfma ----
#pragma unroll
                for (int kc = 0; kc < 2; ++kc) {
                    union { unsigned int u[4]; bf16x8 v; } pf;
                    pf.u[0] = pkbf(s[2 * kc][0], s[2 * kc][1]);
                    pf.u[1] = pkbf(s[2 * kc][2], s[2 * kc][3]);
                    pf.u[2] = pkbf(s[2 * kc + 1][0], s[2 * kc + 1][1]);
                    pf.u[3] = pkbf(s[2 * kc + 1][2], s[2 * kc + 1][3]);
                    __builtin_amdgcn_s_setprio(1);
#pragma unroll
                    for (int dt = 0; dt < 4; ++dt) {
                        bf16x8 vf = *(const bf16x8*)
                            &Vt[sub][swz8(dt * 16 + l15, kc * 4 + lhi)];
                        oacc[dt] = mfma16(pf.v, vf, oacc[dt]);
                    }
                    __builtin_amdgcn_s_setprio(0);
                }
            }
        }

        __syncthreads();  // all LDS reads of this 128-tile done
        if (kt + 1 < NT2) {
            write_lds();
            __syncthreads();  // writes visible before next compute
        }
    }

    // ---- output: redistribute l to accumulator rows, store ----
    float lR[4];
#pragma unroll
    for (int r = 0; r < 4; ++r)
        lR[r] = __shfl(l_s, (lane & 48) | (lhi * 4 + r));
#pragma unroll
    for (int dt = 0; dt < 4; ++dt)
#pragma unroll
        for (int r = 0; r < 4; ++r) {
            int qg = q0w + lhi * 4 + r;
            int dg = dt * 16 + l15;
            float val = oacc[dt][r] / lR[r];
            O[(size_t)qg * DMODEL + h * DK + dg] = __float2bfloat16(val);
        }
}

extern "C" void kernel_launch(void* const* d_in, const int* in_sizes, int n_in,
                              void* d_out, int out_size, void* d_ws, size_t ws_size,
                              hipStream_t stream) {
    const float* x  = (const float*)d_in[0];
    const float* Wq = (const float*)d_in[1];
    const float* Wk = (const float*)d_in[2];
    const float* Wv = (const float*)d_in[3];
    const float* Wo = (const float*)d_in[4];
    float* out = (float*)d_out;

    bf16* q_ws = (bf16*)d_ws;                    // [H][S][64] bf16
    bf16* k_ws = q_ws + (size_t)S_LEN * DMODEL;  // [H][S][64] bf16
    bf16* v_ws = k_ws + (size_t)S_LEN * DMODEL;  // [H][64][S] bf16 (V^T)
    bf16* a_ws = v_ws + (size_t)S_LEN * DMODEL;  // [S][D] bf16

    dim3 gq(256, 1, 3);
    qkv_proj<<<gq, 256, 0, stream>>>(x, Wq, Wk, Wv, q_ws, k_ws, v_ws);
    attn_kernel<<<1024, 256, 0, stream>>>(q_ws, k_ws, v_ws, a_ws);
    out_proj<<<256, 256, 0, stream>>>(a_ws, Wo, out);
}